// Round 1
// baseline (976.125 us; speedup 1.0000x reference)
//
#include <hip/hip_runtime.h>
#include <hip/hip_bf16.h>
#include <cstdint>

#define N_NODESC  102400
#define N_EDGESC  1638400
#define NUM_GRAPHS 128
#define NPG       800
#define HID       128
#define BN_EPS    1e-5f

// ----------------- CSR build -----------------
__global__ void k_count(const int* __restrict__ ei, int* __restrict__ deg){
    int e = blockIdx.x*blockDim.x + threadIdx.x;
    if (e < N_EDGESC) atomicAdd(&deg[ei[N_EDGESC + e]], 1);
}

__global__ __launch_bounds__(1024) void k_scan_a(const int* __restrict__ deg, int* __restrict__ row_ptr,
                                                 float* __restrict__ dinv, int* __restrict__ chunkTot){
    __shared__ int sh[1024];
    int t = threadIdx.x;
    int i = blockIdx.x*1024 + t;
    int v = deg[i];
    dinv[i] = rsqrtf((float)(v + 1));   // +1 self loop
    sh[t] = v;
    __syncthreads();
    for (int off = 1; off < 1024; off <<= 1){
        int add = (t >= off) ? sh[t - off] : 0;
        __syncthreads();
        sh[t] += add;
        __syncthreads();
    }
    row_ptr[i] = sh[t] - v;             // exclusive within chunk
    if (t == 1023) chunkTot[blockIdx.x] = sh[t];
}

__global__ __launch_bounds__(128) void k_scan_b(const int* __restrict__ chunkTot, int* __restrict__ chunkOff,
                                                int* __restrict__ row_ptr){
    __shared__ int sh[128];
    int t = threadIdx.x;
    int v = (t < 100) ? chunkTot[t] : 0;
    sh[t] = v;
    __syncthreads();
    for (int off = 1; off < 128; off <<= 1){
        int add = (t >= off) ? sh[t - off] : 0;
        __syncthreads();
        sh[t] += add;
        __syncthreads();
    }
    if (t < 100) chunkOff[t] = sh[t] - v;
    if (t == 0)  row_ptr[N_NODESC] = N_EDGESC;
}

__global__ __launch_bounds__(1024) void k_scan_c(int* __restrict__ row_ptr, const int* __restrict__ chunkOff){
    int i = blockIdx.x*1024 + threadIdx.x;
    row_ptr[i] += chunkOff[blockIdx.x];
}

__global__ void k_scatter(const int* __restrict__ ei, const int* __restrict__ row_ptr,
                          int* __restrict__ cursor, const float* __restrict__ dinv,
                          int* __restrict__ srcS, float* __restrict__ normS){
    int e = blockIdx.x*blockDim.x + threadIdx.x;
    if (e < N_EDGESC){
        int s = ei[e];
        int d = ei[N_EDGESC + e];
        int pos = row_ptr[d] + atomicAdd(&cursor[d], 1);
        srcS[pos]  = s;
        normS[pos] = dinv[s] * dinv[d];
    }
}

// ----------------- fp32 GEMM: H = X @ W + bias  (M=102400, N=128, K=128) -----------------
__global__ __launch_bounds__(256) void k_gemm(const float* __restrict__ X, const float* __restrict__ W,
                                              const float* __restrict__ bias, float* __restrict__ H){
    __shared__ float xs[16][68];   // transposed x tile [k][m], padded
    __shared__ float wsm[16][68];  // w tile [k][n], padded
    int t  = threadIdx.x;
    int tx = t & 15;               // col group (4 cols each)
    int ty = t >> 4;               // row group (4 rows each)
    int rowBase = blockIdx.x * 64;
    int colBase = blockIdx.y * 64;
    int lr = t >> 2;               // load row 0..63
    int lj = t & 3;                // float4 slot in 16-wide k
    float acc[4][4] = {};
    for (int k0 = 0; k0 < HID; k0 += 16){
        float4 xv = *(const float4*)(X + (size_t)(rowBase + lr)*HID + k0 + lj*4);
        float4 wv = *(const float4*)(W + (size_t)(k0 + ty)*HID + colBase + tx*4);
        xs[lj*4+0][lr] = xv.x; xs[lj*4+1][lr] = xv.y; xs[lj*4+2][lr] = xv.z; xs[lj*4+3][lr] = xv.w;
        *(float4*)&wsm[ty][tx*4] = wv;
        __syncthreads();
        #pragma unroll
        for (int k = 0; k < 16; k++){
            float4 a = *(const float4*)&xs[k][ty*4];
            float4 b = *(const float4*)&wsm[k][tx*4];
            acc[0][0] = fmaf(a.x,b.x,acc[0][0]); acc[0][1] = fmaf(a.x,b.y,acc[0][1]);
            acc[0][2] = fmaf(a.x,b.z,acc[0][2]); acc[0][3] = fmaf(a.x,b.w,acc[0][3]);
            acc[1][0] = fmaf(a.y,b.x,acc[1][0]); acc[1][1] = fmaf(a.y,b.y,acc[1][1]);
            acc[1][2] = fmaf(a.y,b.z,acc[1][2]); acc[1][3] = fmaf(a.y,b.w,acc[1][3]);
            acc[2][0] = fmaf(a.z,b.x,acc[2][0]); acc[2][1] = fmaf(a.z,b.y,acc[2][1]);
            acc[2][2] = fmaf(a.z,b.z,acc[2][2]); acc[2][3] = fmaf(a.z,b.w,acc[2][3]);
            acc[3][0] = fmaf(a.w,b.x,acc[3][0]); acc[3][1] = fmaf(a.w,b.y,acc[3][1]);
            acc[3][2] = fmaf(a.w,b.z,acc[3][2]); acc[3][3] = fmaf(a.w,b.w,acc[3][3]);
        }
        __syncthreads();
    }
    float4 bv = *(const float4*)(bias + colBase + tx*4);
    #pragma unroll
    for (int i = 0; i < 4; i++){
        float4 o;
        o.x = acc[i][0] + bv.x; o.y = acc[i][1] + bv.y;
        o.z = acc[i][2] + bv.z; o.w = acc[i][3] + bv.w;
        *(float4*)(H + (size_t)(rowBase + ty*4 + i)*HID + colBase + tx*4) = o;
    }
}

// ----------------- aggregation: OUT[v] = relu(sum_in norm*h[src] + h[v]/deg + b) -----------------
__global__ __launch_bounds__(256) void k_agg(const float* __restrict__ H, const int* __restrict__ row_ptr,
                                             const int* __restrict__ srcS, const float* __restrict__ normS,
                                             const float* __restrict__ dinv, const float* __restrict__ bconv,
                                             float* __restrict__ OUT){
    const float2* H2 = (const float2*)H;
    float2* O2 = (float2*)OUT;
    int lane = threadIdx.x & 63;
    int wave = blockIdx.x*(blockDim.x >> 6) + (threadIdx.x >> 6);
    int nw   = gridDim.x*(blockDim.x >> 6);
    float2 bc = ((const float2*)bconv)[lane];
    for (int n = wave; n < N_NODESC; n += nw){
        int e0 = row_ptr[n], e1 = row_ptr[n+1];
        float ax = 0.f, ay = 0.f;
        for (int e = e0; e < e1; e++){
            int s   = srcS[e];
            float w = normS[e];
            float2 h = H2[(size_t)s*64 + lane];
            ax = fmaf(w, h.x, ax); ay = fmaf(w, h.y, ay);
        }
        float di = dinv[n]; float wself = di*di;
        float2 hn = H2[(size_t)n*64 + lane];
        ax = fmaf(wself, hn.x, ax); ay = fmaf(wself, hn.y, ay);
        ax = fmaxf(ax + bc.x, 0.f); ay = fmaxf(ay + bc.y, 0.f);
        float2 o; o.x = ax; o.y = ay;
        O2[(size_t)n*64 + lane] = o;
    }
}

// ----------------- column stats (sum, sumsq) -----------------
__global__ __launch_bounds__(256) void k_stats(const float* __restrict__ X, float* __restrict__ sum,
                                               float* __restrict__ sumsq){
    int t = threadIdx.x;
    int ch = t & 127, half = t >> 7;
    float s = 0.f, s2 = 0.f;
    for (int n = blockIdx.x*2 + half; n < N_NODESC; n += gridDim.x*2){
        float v = X[(size_t)n*HID + ch];
        s += v; s2 = fmaf(v, v, s2);
    }
    __shared__ float sh[256];
    sh[t] = s; __syncthreads();
    if (half == 0) atomicAdd(&sum[ch], sh[ch] + sh[128+ch]);
    __syncthreads();
    sh[t] = s2; __syncthreads();
    if (half == 0) atomicAdd(&sumsq[ch], sh[ch] + sh[128+ch]);
}

// ----------------- BN finalize + fold into next W -----------------
__global__ __launch_bounds__(128) void k_finalize(const float* __restrict__ sum, const float* __restrict__ sumsq,
                                                  const float* __restrict__ gamma, const float* __restrict__ beta,
                                                  const float* __restrict__ Wnext, float* __restrict__ A,
                                                  float* __restrict__ B, float* __restrict__ Wp,
                                                  float* __restrict__ biasv, int hasNext){
    __shared__ float Ash[128], Bsh[128];
    int c = threadIdx.x;
    const float invN = 1.0f / (float)N_NODESC;
    float mu  = sum[c] * invN;
    float var = sumsq[c] * invN - mu*mu;
    float is  = rsqrtf(var + BN_EPS);
    float a = is * gamma[c];
    float b = beta[c] - mu * a;
    A[c] = a; B[c] = b; Ash[c] = a; Bsh[c] = b;
    __syncthreads();
    if (hasNext){
        float bv = 0.f;
        for (int k = 0; k < 128; k++){
            float w = Wnext[k*128 + c];
            Wp[k*128 + c] = Ash[k] * w;
            bv = fmaf(Bsh[k], w, bv);
        }
        biasv[c] = bv;
    }
}

// ----------------- readout pooling (max, mean, first) with BN applied inline -----------------
__global__ __launch_bounds__(1024) void k_pool(const float* __restrict__ X, const float* __restrict__ A,
                                               const float* __restrict__ B, float* __restrict__ g){
    __shared__ float shm[8][128];
    __shared__ float shs[8][128];
    int t = threadIdx.x;
    int c = t & 127, sl = t >> 7;    // 8 slices x 100 nodes
    int gr = blockIdx.x;
    float a = A[c], b = B[c];
    const float* base = X + ((size_t)gr*NPG + sl*100)*HID;
    float mx = -1e30f, sm = 0.f;
    for (int i = 0; i < 100; i++){
        float v = fmaf(base[(size_t)i*HID + c], a, b);
        mx = fmaxf(mx, v); sm += v;
    }
    shm[sl][c] = mx; shs[sl][c] = sm;
    if (sl == 0) g[gr*384 + 256 + c] = fmaf(base[c], a, b);   // first node of graph
    __syncthreads();
    if (t < 128){
        float m = shm[0][t], s = shs[0][t];
        #pragma unroll
        for (int q = 1; q < 8; q++){ m = fmaxf(m, shm[q][t]); s += shs[q][t]; }
        g[gr*384 + t]       = m;
        g[gr*384 + 128 + t] = s * (1.0f/(float)NPG);
    }
}

// ----------------- MLP + log_softmax -----------------
__global__ __launch_bounds__(512) void k_mlp(const float* __restrict__ g, const float* __restrict__ W1,
                                             const float* __restrict__ b1, const float* __restrict__ W2,
                                             const float* __restrict__ b2, float* __restrict__ out){
    __shared__ float row[384];
    __shared__ float t1[384];
    __shared__ float r0[512], r1[512];
    int t = threadIdx.x, gr = blockIdx.x;
    if (t < 384) row[t] = g[gr*384 + t];
    __syncthreads();
    if (t < 384){
        float acc = b1[t];
        for (int k = 0; k < 384; k++) acc = fmaf(row[k], W1[(size_t)k*384 + t], acc);
        t1[t] = acc;
    }
    __syncthreads();
    float p0 = 0.f, p1 = 0.f;
    if (t < 384){ float v = t1[t]; p0 = v*W2[t*2]; p1 = v*W2[t*2+1]; }
    r0[t] = p0; r1[t] = p1; __syncthreads();
    for (int off = 256; off > 0; off >>= 1){
        if (t < off){ r0[t] += r0[t+off]; r1[t] += r1[t+off]; }
        __syncthreads();
    }
    if (t == 0){
        float o0 = r0[0] + b2[0], o1 = r1[0] + b2[1];
        float m = fmaxf(o0, o1);
        float lse = m + logf(expf(o0 - m) + expf(o1 - m));
        out[gr*2 + 0] = o0 - lse;
        out[gr*2 + 1] = o1 - lse;
    }
}

extern "C" void kernel_launch(void* const* d_in, const int* in_sizes, int n_in,
                              void* d_out, int out_size, void* d_ws, size_t ws_size,
                              hipStream_t stream){
    const float* x     = (const float*)d_in[0];
    const int*   ei    = (const int*)d_in[1];     // [2][N_EDGES], int32
    // d_in[2] = batch: uniform 800 nodes/graph, computed implicitly
    const float* Wconv = (const float*)d_in[3];   // [3][128][128]
    const float* bconv = (const float*)d_in[4];   // [3][128]
    const float* gamma = (const float*)d_in[5];
    const float* beta  = (const float*)d_in[6];
    const float* W1    = (const float*)d_in[7];   // [384][384]
    const float* b1    = (const float*)d_in[8];
    const float* W2    = (const float*)d_in[9];   // [384][2]
    const float* b2    = (const float*)d_in[10];
    float* out = (float*)d_out;

    // workspace carve-up (~120 MB needed)
    char* p = (char*)d_ws;
    size_t off = 0;
    auto alloc = [&](size_t bytes)->char* {
        char* r = p + off; off += (bytes + 255) & ~(size_t)255; return r;
    };
    float* buf1    = (float*)alloc((size_t)N_NODESC*HID*4);  // h = x@W
    float* buf2    = (float*)alloc((size_t)N_NODESC*HID*4);  // post-agg relu'd
    int*   srcS    = (int*)  alloc((size_t)N_EDGESC*4);
    float* normS   = (float*)alloc((size_t)N_EDGESC*4);
    int*   row_ptr = (int*)  alloc((size_t)(N_NODESC+1)*4);
    int*   deg     = (int*)  alloc((size_t)N_NODESC*4);      // reused as scatter cursor
    float* dinv    = (float*)alloc((size_t)N_NODESC*4);
    int*   chunkTot= (int*)  alloc(512);
    int*   chunkOff= (int*)  alloc(512);
    float* stats   = (float*)alloc(3*2*128*4);               // [l][sum|sumsq][128]
    float* AB      = (float*)alloc(3*2*128*4);               // [l][A|B][128]
    float* Wp      = (float*)alloc(128*128*4);               // BN-folded next-layer W
    float* biasv   = (float*)alloc(512);                     // BN-folded bias (zeros for layer 0)
    float* g       = (float*)alloc((size_t)NUM_GRAPHS*384*4);
    (void)ws_size; (void)in_sizes; (void)n_in; (void)out_size;

    hipMemsetAsync(deg,   0, (size_t)N_NODESC*4, stream);
    hipMemsetAsync(stats, 0, 3*2*128*4, stream);
    hipMemsetAsync(biasv, 0, 512, stream);

    k_count  <<<(N_EDGESC+255)/256, 256, 0, stream>>>(ei, deg);
    k_scan_a <<<N_NODESC/1024, 1024, 0, stream>>>(deg, row_ptr, dinv, chunkTot);
    k_scan_b <<<1, 128, 0, stream>>>(chunkTot, chunkOff, row_ptr);
    k_scan_c <<<N_NODESC/1024, 1024, 0, stream>>>(row_ptr, chunkOff);
    hipMemsetAsync(deg, 0, (size_t)N_NODESC*4, stream);      // cursor for scatter
    k_scatter<<<(N_EDGESC+255)/256, 256, 0, stream>>>(ei, row_ptr, deg, dinv, srcS, normS);

    const float* gin = x;
    for (int l = 0; l < 3; l++){
        const float* Wl = (l == 0) ? Wconv : Wp;
        k_gemm <<<dim3(N_NODESC/64, 2), 256, 0, stream>>>(gin, Wl, biasv, buf1);
        k_agg  <<<2048, 256, 0, stream>>>(buf1, row_ptr, srcS, normS, dinv, bconv + l*HID, buf2);
        k_stats<<<1024, 256, 0, stream>>>(buf2, stats + l*256, stats + l*256 + 128);
        k_finalize<<<1, 128, 0, stream>>>(stats + l*256, stats + l*256 + 128,
                                          gamma + l*HID, beta + l*HID,
                                          Wconv + (size_t)(l+1 < 3 ? l+1 : 0)*HID*HID,
                                          AB + l*256, AB + l*256 + 128,
                                          Wp, biasv, (l < 2) ? 1 : 0);
        gin = buf2;
    }
    k_pool<<<NUM_GRAPHS, 1024, 0, stream>>>(buf2, AB + 2*256, AB + 2*256 + 128, g);
    k_mlp <<<NUM_GRAPHS, 512, 0, stream>>>(g, W1, b1, W2, b2, out);
}

// Round 2
// 694.915 us; speedup vs baseline: 1.4047x; 1.4047x over previous
//
#include <hip/hip_runtime.h>
#include <hip/hip_bf16.h>
#include <cstdint>

#define N_NODESC  102400
#define N_EDGESC  1638400
#define NUM_GRAPHS 128
#define NPG       800
#define HID       128
#define BN_EPS    1e-5f

__device__ __forceinline__ unsigned short f2bf(float f){
    union { __hip_bfloat16 h; unsigned short u; } cv;
    cv.h = __float2bfloat16(f);
    return cv.u;
}
__device__ __forceinline__ float bflo(unsigned int g){ return __uint_as_float(g << 16); }
__device__ __forceinline__ float bfhi(unsigned int g){ return __uint_as_float(g & 0xffff0000u); }

// ----------------- CSR build -----------------
__global__ void k_count(const int* __restrict__ ei, int* __restrict__ deg){
    int e = blockIdx.x*blockDim.x + threadIdx.x;
    if (e < N_EDGESC) atomicAdd(&deg[ei[N_EDGESC + e]], 1);
}

__global__ __launch_bounds__(1024) void k_scan_a(const int* __restrict__ deg, int* __restrict__ row_ptr,
                                                 float* __restrict__ dinv, int* __restrict__ chunkTot){
    __shared__ int sh[1024];
    int t = threadIdx.x;
    int i = blockIdx.x*1024 + t;
    int v = deg[i];
    dinv[i] = rsqrtf((float)(v + 1));   // +1 self loop
    sh[t] = v;
    __syncthreads();
    for (int off = 1; off < 1024; off <<= 1){
        int add = (t >= off) ? sh[t - off] : 0;
        __syncthreads();
        sh[t] += add;
        __syncthreads();
    }
    row_ptr[i] = sh[t] - v;             // exclusive within chunk
    if (t == 1023) chunkTot[blockIdx.x] = sh[t];
}

__global__ __launch_bounds__(128) void k_scan_b(const int* __restrict__ chunkTot, int* __restrict__ chunkOff,
                                                int* __restrict__ row_ptr){
    __shared__ int sh[128];
    int t = threadIdx.x;
    int v = (t < 100) ? chunkTot[t] : 0;
    sh[t] = v;
    __syncthreads();
    for (int off = 1; off < 128; off <<= 1){
        int add = (t >= off) ? sh[t - off] : 0;
        __syncthreads();
        sh[t] += add;
        __syncthreads();
    }
    if (t < 100) chunkOff[t] = sh[t] - v;
    if (t == 0)  row_ptr[N_NODESC] = N_EDGESC;
}

__global__ __launch_bounds__(1024) void k_scan_c(int* __restrict__ row_ptr, const int* __restrict__ chunkOff){
    int i = blockIdx.x*1024 + threadIdx.x;
    row_ptr[i] += chunkOff[blockIdx.x];
}

__global__ void k_scatter(const int* __restrict__ ei, const int* __restrict__ row_ptr,
                          int* __restrict__ cursor, const float* __restrict__ dinv,
                          int* __restrict__ srcS, float* __restrict__ normS){
    int e = blockIdx.x*blockDim.x + threadIdx.x;
    if (e < N_EDGESC){
        int s = ei[e];
        int d = ei[N_EDGESC + e];
        int pos = row_ptr[d] + atomicAdd(&cursor[d], 1);
        srcS[pos]  = s;
        normS[pos] = dinv[s] * dinv[d];
    }
}

// ----------------- fp32 GEMM: H = bf16(X @ W + bias)  (M=102400, N=128, K=128) -----------------
__global__ __launch_bounds__(256) void k_gemm(const float* __restrict__ X, const float* __restrict__ W,
                                              const float* __restrict__ bias, unsigned short* __restrict__ H){
    __shared__ float xs[16][68];   // transposed x tile [k][m], padded
    __shared__ float wsm[16][68];  // w tile [k][n], padded
    int t  = threadIdx.x;
    int tx = t & 15;               // col group (4 cols each)
    int ty = t >> 4;               // row group (4 rows each)
    int rowBase = blockIdx.x * 64;
    int colBase = blockIdx.y * 64;
    int lr = t >> 2;               // load row 0..63
    int lj = t & 3;                // float4 slot in 16-wide k
    float acc[4][4] = {};
    for (int k0 = 0; k0 < HID; k0 += 16){
        float4 xv = *(const float4*)(X + (size_t)(rowBase + lr)*HID + k0 + lj*4);
        float4 wv = *(const float4*)(W + (size_t)(k0 + ty)*HID + colBase + tx*4);
        xs[lj*4+0][lr] = xv.x; xs[lj*4+1][lr] = xv.y; xs[lj*4+2][lr] = xv.z; xs[lj*4+3][lr] = xv.w;
        *(float4*)&wsm[ty][tx*4] = wv;
        __syncthreads();
        #pragma unroll
        for (int k = 0; k < 16; k++){
            float4 a = *(const float4*)&xs[k][ty*4];
            float4 b = *(const float4*)&wsm[k][tx*4];
            acc[0][0] = fmaf(a.x,b.x,acc[0][0]); acc[0][1] = fmaf(a.x,b.y,acc[0][1]);
            acc[0][2] = fmaf(a.x,b.z,acc[0][2]); acc[0][3] = fmaf(a.x,b.w,acc[0][3]);
            acc[1][0] = fmaf(a.y,b.x,acc[1][0]); acc[1][1] = fmaf(a.y,b.y,acc[1][1]);
            acc[1][2] = fmaf(a.y,b.z,acc[1][2]); acc[1][3] = fmaf(a.y,b.w,acc[1][3]);
            acc[2][0] = fmaf(a.z,b.x,acc[2][0]); acc[2][1] = fmaf(a.z,b.y,acc[2][1]);
            acc[2][2] = fmaf(a.z,b.z,acc[2][2]); acc[2][3] = fmaf(a.z,b.w,acc[2][3]);
            acc[3][0] = fmaf(a.w,b.x,acc[3][0]); acc[3][1] = fmaf(a.w,b.y,acc[3][1]);
            acc[3][2] = fmaf(a.w,b.z,acc[3][2]); acc[3][3] = fmaf(a.w,b.w,acc[3][3]);
        }
        __syncthreads();
    }
    float4 bv = *(const float4*)(bias + colBase + tx*4);
    #pragma unroll
    for (int i = 0; i < 4; i++){
        ushort4 o;
        o.x = f2bf(acc[i][0] + bv.x); o.y = f2bf(acc[i][1] + bv.y);
        o.z = f2bf(acc[i][2] + bv.z); o.w = f2bf(acc[i][3] + bv.w);
        *(ushort4*)(H + (size_t)(rowBase + ty*4 + i)*HID + colBase + tx*4) = o;
    }
}

// --------- aggregation + relu + fused BN stats: OUT[v] = relu(sum norm*h[src] + h[v]*dinv^2 + b) ---------
__global__ __launch_bounds__(256) void k_agg(const unsigned int* __restrict__ Hb, const int* __restrict__ row_ptr,
                                             const int* __restrict__ srcS, const float* __restrict__ normS,
                                             const float* __restrict__ dinv, const float* __restrict__ bconv,
                                             float* __restrict__ OUT, float* __restrict__ sum,
                                             float* __restrict__ sumsq){
    int lane = threadIdx.x & 63;
    int w    = threadIdx.x >> 6;
    int wave = blockIdx.x*4 + w;
    int nw   = gridDim.x*4;
    float2 bc = ((const float2*)bconv)[lane];
    float2* O2 = (float2*)OUT;
    float sx0 = 0.f, sx1 = 0.f, sq0 = 0.f, sq1 = 0.f;
    for (int n = wave; n < N_NODESC; n += nw){
        int e0 = row_ptr[n], e1 = row_ptr[n+1];
        float ax = 0.f, ay = 0.f;
        int e = e0;
        for (; e + 4 <= e1; e += 4){
            int s0 = srcS[e], s1 = srcS[e+1], s2 = srcS[e+2], s3 = srcS[e+3];
            float n0 = normS[e], n1 = normS[e+1], n2 = normS[e+2], n3 = normS[e+3];
            unsigned int g0 = Hb[(size_t)s0*64 + lane];
            unsigned int g1 = Hb[(size_t)s1*64 + lane];
            unsigned int g2 = Hb[(size_t)s2*64 + lane];
            unsigned int g3 = Hb[(size_t)s3*64 + lane];
            ax = fmaf(n0, bflo(g0), ax); ay = fmaf(n0, bfhi(g0), ay);
            ax = fmaf(n1, bflo(g1), ax); ay = fmaf(n1, bfhi(g1), ay);
            ax = fmaf(n2, bflo(g2), ax); ay = fmaf(n2, bfhi(g2), ay);
            ax = fmaf(n3, bflo(g3), ax); ay = fmaf(n3, bfhi(g3), ay);
        }
        for (; e < e1; e++){
            int s = srcS[e];
            float nv = normS[e];
            unsigned int g = Hb[(size_t)s*64 + lane];
            ax = fmaf(nv, bflo(g), ax); ay = fmaf(nv, bfhi(g), ay);
        }
        float di = dinv[n]; float ws = di*di;
        unsigned int gn = Hb[(size_t)n*64 + lane];
        ax = fmaf(ws, bflo(gn), ax); ay = fmaf(ws, bfhi(gn), ay);
        ax = fmaxf(ax + bc.x, 0.f); ay = fmaxf(ay + bc.y, 0.f);
        float2 o; o.x = ax; o.y = ay;
        O2[(size_t)n*64 + lane] = o;
        sx0 += ax; sq0 = fmaf(ax, ax, sq0);
        sx1 += ay; sq1 = fmaf(ay, ay, sq1);
    }
    __shared__ float shs[4][128];
    __shared__ float shq[4][128];
    shs[w][2*lane]   = sx0; shs[w][2*lane+1] = sx1;
    shq[w][2*lane]   = sq0; shq[w][2*lane+1] = sq1;
    __syncthreads();
    int t = threadIdx.x;
    if (t < 128){
        atomicAdd(&sum[t],   shs[0][t] + shs[1][t] + shs[2][t] + shs[3][t]);
        atomicAdd(&sumsq[t], shq[0][t] + shq[1][t] + shq[2][t] + shq[3][t]);
    }
}

// ----------------- BN finalize + fold into next W -----------------
__global__ __launch_bounds__(128) void k_finalize(const float* __restrict__ sum, const float* __restrict__ sumsq,
                                                  const float* __restrict__ gamma, const float* __restrict__ beta,
                                                  const float* __restrict__ Wnext, float* __restrict__ A,
                                                  float* __restrict__ B, float* __restrict__ Wp,
                                                  float* __restrict__ biasv, int hasNext){
    __shared__ float Ash[128], Bsh[128];
    int c = threadIdx.x;
    const float invN = 1.0f / (float)N_NODESC;
    float mu  = sum[c] * invN;
    float var = sumsq[c] * invN - mu*mu;
    float is  = rsqrtf(var + BN_EPS);
    float a = is * gamma[c];
    float b = beta[c] - mu * a;
    A[c] = a; B[c] = b; Ash[c] = a; Bsh[c] = b;
    __syncthreads();
    if (hasNext){
        float bv = 0.f;
        for (int k = 0; k < 128; k++){
            float w = Wnext[k*128 + c];
            Wp[k*128 + c] = Ash[k] * w;
            bv = fmaf(Bsh[k], w, bv);
        }
        biasv[c] = bv;
    }
}

// ----------------- readout pooling (max, mean, first) with BN applied inline -----------------
__global__ __launch_bounds__(1024) void k_pool(const float* __restrict__ X, const float* __restrict__ A,
                                               const float* __restrict__ B, float* __restrict__ g){
    __shared__ float shm[8][128];
    __shared__ float shs[8][128];
    int t = threadIdx.x;
    int c = t & 127, sl = t >> 7;    // 8 slices x 100 nodes
    int gr = blockIdx.x;
    float a = A[c], b = B[c];
    const float* base = X + ((size_t)gr*NPG + sl*100)*HID;
    float mx = -1e30f, sm = 0.f;
    for (int i = 0; i < 100; i++){
        float v = fmaf(base[(size_t)i*HID + c], a, b);
        mx = fmaxf(mx, v); sm += v;
    }
    shm[sl][c] = mx; shs[sl][c] = sm;
    if (sl == 0) g[gr*384 + 256 + c] = fmaf(base[c], a, b);   // first node of graph
    __syncthreads();
    if (t < 128){
        float m = shm[0][t], s = shs[0][t];
        #pragma unroll
        for (int q = 1; q < 8; q++){ m = fmaxf(m, shm[q][t]); s += shs[q][t]; }
        g[gr*384 + t]       = m;
        g[gr*384 + 128 + t] = s * (1.0f/(float)NPG);
    }
}

// ----------------- MLP + log_softmax -----------------
__global__ __launch_bounds__(512) void k_mlp(const float* __restrict__ g, const float* __restrict__ W1,
                                             const float* __restrict__ b1, const float* __restrict__ W2,
                                             const float* __restrict__ b2, float* __restrict__ out){
    __shared__ float row[384];
    __shared__ float t1[384];
    __shared__ float r0[512], r1[512];
    int t = threadIdx.x, gr = blockIdx.x;
    if (t < 384) row[t] = g[gr*384 + t];
    __syncthreads();
    if (t < 384){
        float acc = b1[t];
        for (int k = 0; k < 384; k++) acc = fmaf(row[k], W1[(size_t)k*384 + t], acc);
        t1[t] = acc;
    }
    __syncthreads();
    float p0 = 0.f, p1 = 0.f;
    if (t < 384){ float v = t1[t]; p0 = v*W2[t*2]; p1 = v*W2[t*2+1]; }
    r0[t] = p0; r1[t] = p1; __syncthreads();
    for (int off = 256; off > 0; off >>= 1){
        if (t < off){ r0[t] += r0[t+off]; r1[t] += r1[t+off]; }
        __syncthreads();
    }
    if (t == 0){
        float o0 = r0[0] + b2[0], o1 = r1[0] + b2[1];
        float m = fmaxf(o0, o1);
        float lse = m + logf(expf(o0 - m) + expf(o1 - m));
        out[gr*2 + 0] = o0 - lse;
        out[gr*2 + 1] = o1 - lse;
    }
}

extern "C" void kernel_launch(void* const* d_in, const int* in_sizes, int n_in,
                              void* d_out, int out_size, void* d_ws, size_t ws_size,
                              hipStream_t stream){
    const float* x     = (const float*)d_in[0];
    const int*   ei    = (const int*)d_in[1];     // [2][N_EDGES]
    const float* Wconv = (const float*)d_in[3];   // [3][128][128]
    const float* bconv = (const float*)d_in[4];   // [3][128]
    const float* gamma = (const float*)d_in[5];
    const float* beta  = (const float*)d_in[6];
    const float* W1    = (const float*)d_in[7];   // [384][384]
    const float* b1    = (const float*)d_in[8];
    const float* W2    = (const float*)d_in[9];   // [384][2]
    const float* b2    = (const float*)d_in[10];
    float* out = (float*)d_out;

    char* p = (char*)d_ws;
    size_t off = 0;
    auto alloc = [&](size_t bytes)->char* {
        char* r = p + off; off += (bytes + 255) & ~(size_t)255; return r;
    };
    unsigned short* buf1 = (unsigned short*)alloc((size_t)N_NODESC*HID*2);  // h = bf16(x@W)
    float* buf2    = (float*)alloc((size_t)N_NODESC*HID*4);  // post-agg relu'd (fp32)
    int*   srcS    = (int*)  alloc((size_t)N_EDGESC*4);
    float* normS   = (float*)alloc((size_t)N_EDGESC*4);
    int*   row_ptr = (int*)  alloc((size_t)(N_NODESC+1)*4);
    int*   deg     = (int*)  alloc((size_t)N_NODESC*4);      // reused as scatter cursor
    float* dinv    = (float*)alloc((size_t)N_NODESC*4);
    int*   chunkTot= (int*)  alloc(512);
    int*   chunkOff= (int*)  alloc(512);
    float* stats   = (float*)alloc(3*2*128*4);               // [l][sum|sumsq][128]
    float* AB      = (float*)alloc(3*2*128*4);               // [l][A|B][128]
    float* Wp      = (float*)alloc(128*128*4);               // BN-folded next-layer W
    float* biasv   = (float*)alloc(512);                     // BN-folded bias (zeros for layer 0)
    float* g       = (float*)alloc((size_t)NUM_GRAPHS*384*4);
    (void)ws_size; (void)in_sizes; (void)n_in; (void)out_size;

    hipMemsetAsync(deg,   0, (size_t)N_NODESC*4, stream);
    hipMemsetAsync(stats, 0, 3*2*128*4, stream);
    hipMemsetAsync(biasv, 0, 512, stream);

    k_count  <<<(N_EDGESC+255)/256, 256, 0, stream>>>(ei, deg);
    k_scan_a <<<N_NODESC/1024, 1024, 0, stream>>>(deg, row_ptr, dinv, chunkTot);
    k_scan_b <<<1, 128, 0, stream>>>(chunkTot, chunkOff, row_ptr);
    k_scan_c <<<N_NODESC/1024, 1024, 0, stream>>>(row_ptr, chunkOff);
    hipMemsetAsync(deg, 0, (size_t)N_NODESC*4, stream);      // cursor for scatter
    k_scatter<<<(N_EDGESC+255)/256, 256, 0, stream>>>(ei, row_ptr, deg, dinv, srcS, normS);

    const float* gin = x;
    for (int l = 0; l < 3; l++){
        const float* Wl = (l == 0) ? Wconv : Wp;
        k_gemm <<<dim3(N_NODESC/64, 2), 256, 0, stream>>>(gin, Wl, biasv, buf1);
        k_agg  <<<2048, 256, 0, stream>>>((const unsigned int*)buf1, row_ptr, srcS, normS, dinv,
                                          bconv + l*HID, buf2,
                                          stats + l*256, stats + l*256 + 128);
        k_finalize<<<1, 128, 0, stream>>>(stats + l*256, stats + l*256 + 128,
                                          gamma + l*HID, beta + l*HID,
                                          Wconv + (size_t)(l+1 < 3 ? l+1 : 0)*HID*HID,
                                          AB + l*256, AB + l*256 + 128,
                                          Wp, biasv, (l < 2) ? 1 : 0);
        gin = buf2;
    }
    k_pool<<<NUM_GRAPHS, 1024, 0, stream>>>(buf2, AB + 2*256, AB + 2*256 + 128, g);
    k_mlp <<<NUM_GRAPHS, 512, 0, stream>>>(g, W1, b1, W2, b2, out);
}

// Round 3
// 647.059 us; speedup vs baseline: 1.5086x; 1.0740x over previous
//
#include <hip/hip_runtime.h>
#include <hip/hip_bf16.h>
#include <cstdint>

#define N_NODESC  102400
#define N_EDGESC  1638400
#define NUM_GRAPHS 128
#define NPG       800
#define HID       128
#define BN_EPS    1e-5f

typedef short short8 __attribute__((ext_vector_type(8)));
typedef float f32x4  __attribute__((ext_vector_type(4)));

__device__ __forceinline__ unsigned short f2bf(float f){
    union { __hip_bfloat16 h; unsigned short u; } cv;
    cv.h = __float2bfloat16(f);
    return cv.u;
}
__device__ __forceinline__ float bflo(unsigned int g){ return __uint_as_float(g << 16); }
__device__ __forceinline__ float bfhi(unsigned int g){ return __uint_as_float(g & 0xffff0000u); }
__device__ __forceinline__ float bfu(unsigned short u){ return __uint_as_float(((unsigned int)u) << 16); }

// ----------------- CSR build -----------------
__global__ void k_count(const int* __restrict__ ei, int* __restrict__ deg){
    int e = blockIdx.x*blockDim.x + threadIdx.x;
    if (e < N_EDGESC) atomicAdd(&deg[ei[N_EDGESC + e]], 1);
}

__global__ __launch_bounds__(1024) void k_scan_a(const int* __restrict__ deg, int* __restrict__ row_ptr,
                                                 float* __restrict__ dinv, int* __restrict__ chunkTot){
    __shared__ int sh[1024];
    int t = threadIdx.x;
    int i = blockIdx.x*1024 + t;
    int v = deg[i];
    dinv[i] = rsqrtf((float)(v + 1));   // +1 self loop
    sh[t] = v;
    __syncthreads();
    for (int off = 1; off < 1024; off <<= 1){
        int add = (t >= off) ? sh[t - off] : 0;
        __syncthreads();
        sh[t] += add;
        __syncthreads();
    }
    row_ptr[i] = sh[t] - v;
    if (t == 1023) chunkTot[blockIdx.x] = sh[t];
}

__global__ __launch_bounds__(128) void k_scan_b(const int* __restrict__ chunkTot, int* __restrict__ chunkOff,
                                                int* __restrict__ row_ptr){
    __shared__ int sh[128];
    int t = threadIdx.x;
    int v = (t < 100) ? chunkTot[t] : 0;
    sh[t] = v;
    __syncthreads();
    for (int off = 1; off < 128; off <<= 1){
        int add = (t >= off) ? sh[t - off] : 0;
        __syncthreads();
        sh[t] += add;
        __syncthreads();
    }
    if (t < 100) chunkOff[t] = sh[t] - v;
    if (t == 0)  row_ptr[N_NODESC] = N_EDGESC;
}

__global__ __launch_bounds__(1024) void k_scan_c(int* __restrict__ row_ptr, const int* __restrict__ chunkOff){
    int i = blockIdx.x*1024 + threadIdx.x;
    row_ptr[i] += chunkOff[blockIdx.x];
}

__global__ void k_scatter(const int* __restrict__ ei, const int* __restrict__ row_ptr,
                          int* __restrict__ cursor, const float* __restrict__ dinv,
                          int* __restrict__ srcS, float* __restrict__ normS){
    int e = blockIdx.x*blockDim.x + threadIdx.x;
    if (e < N_EDGESC){
        int s = ei[e];
        int d = ei[N_EDGESC + e];
        int pos = row_ptr[d] + atomicAdd(&cursor[d], 1);
        srcS[pos]  = s;
        normS[pos] = dinv[s] * dinv[d];
    }
}

// ----------------- W0^T in bf16 -----------------
__global__ __launch_bounds__(256) void k_prepw0(const float* __restrict__ W, unsigned short* __restrict__ Wt){
    int idx = blockIdx.x*256 + threadIdx.x;          // 16384 elements
    int n = idx & 127, k = idx >> 7;
    Wt[n*128 + k] = f2bf(W[k*128 + n]);
}

// ----------------- MFMA bf16 GEMM: H = bf16(X @ W + biasv), W given as Wt[n][k] bf16 -----------------
// M=102400, N=K=128. 4 waves/block, wave computes 16 rows x 128 cols. No LDS.
template<int F32IN>
__global__ __launch_bounds__(256) void k_gemm_mfma(const void* __restrict__ Xin,
        const unsigned short* __restrict__ Wt, const float* __restrict__ biasv,
        unsigned short* __restrict__ H){
    int l   = threadIdx.x & 63;
    int wid = threadIdx.x >> 6;
    int R   = blockIdx.x*64 + wid*16;
    int r0  = l & 15;          // A-row / B-col / D-col within fragment
    int kg  = l >> 4;          // 8-wide k group
    short8 a[4];
    if (F32IN){
        const float* X = (const float*)Xin;
        #pragma unroll
        for (int kk = 0; kk < 4; kk++){
            const float* p = X + (size_t)(R + r0)*HID + kk*32 + kg*8;
            float4 u = *(const float4*)p;
            float4 v = *(const float4*)(p + 4);
            short8 t;
            t[0]=(short)f2bf(u.x); t[1]=(short)f2bf(u.y); t[2]=(short)f2bf(u.z); t[3]=(short)f2bf(u.w);
            t[4]=(short)f2bf(v.x); t[5]=(short)f2bf(v.y); t[6]=(short)f2bf(v.z); t[7]=(short)f2bf(v.w);
            a[kk] = t;
        }
    } else {
        const unsigned short* X = (const unsigned short*)Xin;
        #pragma unroll
        for (int kk = 0; kk < 4; kk++)
            a[kk] = *(const short8*)(X + (size_t)(R + r0)*HID + kk*32 + kg*8);
    }
    f32x4 acc[8];
    #pragma unroll
    for (int i = 0; i < 8; i++) acc[i] = (f32x4)(0.f);
    #pragma unroll
    for (int kk = 0; kk < 4; kk++){
        #pragma unroll
        for (int nf = 0; nf < 8; nf++){
            short8 b = *(const short8*)(Wt + (size_t)(nf*16 + r0)*HID + kk*32 + kg*8);
            acc[nf] = __builtin_amdgcn_mfma_f32_16x16x32_bf16(a[kk], b, acc[nf], 0, 0, 0);
        }
    }
    #pragma unroll
    for (int nf = 0; nf < 8; nf++){
        float bv = biasv[nf*16 + r0];
        #pragma unroll
        for (int r = 0; r < 4; r++){
            int row = R + kg*4 + r;
            H[(size_t)row*HID + nf*16 + r0] = f2bf(acc[nf][r] + bv);
        }
    }
}

// --------- aggregation + relu + fused BN stats; bf16 in (pairs), bf16 out (pairs) ---------
__global__ __launch_bounds__(256) void k_agg(const unsigned int* __restrict__ Hb, const int* __restrict__ row_ptr,
                                             const int* __restrict__ srcS, const float* __restrict__ normS,
                                             const float* __restrict__ dinv, const float* __restrict__ bconv,
                                             unsigned int* __restrict__ OUT, float* __restrict__ sum,
                                             float* __restrict__ sumsq){
    int lane = threadIdx.x & 63;
    int w    = threadIdx.x >> 6;
    int wave = blockIdx.x*4 + w;
    int nw   = gridDim.x*4;
    float2 bc = ((const float2*)bconv)[lane];
    float sx0 = 0.f, sx1 = 0.f, sq0 = 0.f, sq1 = 0.f;
    for (int n = wave; n < N_NODESC; n += nw){
        int e0 = row_ptr[n], e1 = row_ptr[n+1];
        float ax = 0.f, ay = 0.f;
        int e = e0;
        // scalar prefix to reach 4-alignment (enables aligned int4/float4 metadata loads)
        while (e < e1 && (e & 3)){
            int s = srcS[e]; float nv = normS[e];
            unsigned int g = Hb[(size_t)s*64 + lane];
            ax = fmaf(nv, bflo(g), ax); ay = fmaf(nv, bfhi(g), ay);
            e++;
        }
        // 8-wide main loop: 8 gathers in flight
        for (; e + 8 <= e1; e += 8){
            int4   sa = *(const int4*)(srcS + e);
            int4   sb = *(const int4*)(srcS + e + 4);
            float4 na = *(const float4*)(normS + e);
            float4 nb = *(const float4*)(normS + e + 4);
            unsigned int g0 = Hb[(size_t)sa.x*64 + lane];
            unsigned int g1 = Hb[(size_t)sa.y*64 + lane];
            unsigned int g2 = Hb[(size_t)sa.z*64 + lane];
            unsigned int g3 = Hb[(size_t)sa.w*64 + lane];
            unsigned int g4 = Hb[(size_t)sb.x*64 + lane];
            unsigned int g5 = Hb[(size_t)sb.y*64 + lane];
            unsigned int g6 = Hb[(size_t)sb.z*64 + lane];
            unsigned int g7 = Hb[(size_t)sb.w*64 + lane];
            ax = fmaf(na.x, bflo(g0), ax); ay = fmaf(na.x, bfhi(g0), ay);
            ax = fmaf(na.y, bflo(g1), ax); ay = fmaf(na.y, bfhi(g1), ay);
            ax = fmaf(na.z, bflo(g2), ax); ay = fmaf(na.z, bfhi(g2), ay);
            ax = fmaf(na.w, bflo(g3), ax); ay = fmaf(na.w, bfhi(g3), ay);
            ax = fmaf(nb.x, bflo(g4), ax); ay = fmaf(nb.x, bfhi(g4), ay);
            ax = fmaf(nb.y, bflo(g5), ax); ay = fmaf(nb.y, bfhi(g5), ay);
            ax = fmaf(nb.z, bflo(g6), ax); ay = fmaf(nb.z, bfhi(g6), ay);
            ax = fmaf(nb.w, bflo(g7), ax); ay = fmaf(nb.w, bfhi(g7), ay);
        }
        if (e + 4 <= e1){
            int4   sa = *(const int4*)(srcS + e);
            float4 na = *(const float4*)(normS + e);
            unsigned int g0 = Hb[(size_t)sa.x*64 + lane];
            unsigned int g1 = Hb[(size_t)sa.y*64 + lane];
            unsigned int g2 = Hb[(size_t)sa.z*64 + lane];
            unsigned int g3 = Hb[(size_t)sa.w*64 + lane];
            ax = fmaf(na.x, bflo(g0), ax); ay = fmaf(na.x, bfhi(g0), ay);
            ax = fmaf(na.y, bflo(g1), ax); ay = fmaf(na.y, bfhi(g1), ay);
            ax = fmaf(na.z, bflo(g2), ax); ay = fmaf(na.z, bfhi(g2), ay);
            ax = fmaf(na.w, bflo(g3), ax); ay = fmaf(na.w, bfhi(g3), ay);
            e += 4;
        }
        for (; e < e1; e++){
            int s = srcS[e]; float nv = normS[e];
            unsigned int g = Hb[(size_t)s*64 + lane];
            ax = fmaf(nv, bflo(g), ax); ay = fmaf(nv, bfhi(g), ay);
        }
        float di = dinv[n]; float ws = di*di;
        unsigned int gn = Hb[(size_t)n*64 + lane];
        ax = fmaf(ws, bflo(gn), ax); ay = fmaf(ws, bfhi(gn), ay);
        ax = fmaxf(ax + bc.x, 0.f); ay = fmaxf(ay + bc.y, 0.f);
        unsigned int o = ((unsigned int)f2bf(ay) << 16) | (unsigned int)f2bf(ax);
        __builtin_nontemporal_store(o, &OUT[(size_t)n*64 + lane]);
        sx0 += ax; sq0 = fmaf(ax, ax, sq0);
        sx1 += ay; sq1 = fmaf(ay, ay, sq1);
    }
    __shared__ float shs[4][128];
    __shared__ float shq[4][128];
    shs[w][2*lane]   = sx0; shs[w][2*lane+1] = sx1;
    shq[w][2*lane]   = sq0; shq[w][2*lane+1] = sq1;
    __syncthreads();
    int t = threadIdx.x;
    if (t < 128){
        atomicAdd(&sum[t],   shs[0][t] + shs[1][t] + shs[2][t] + shs[3][t]);
        atomicAdd(&sumsq[t], shq[0][t] + shq[1][t] + shq[2][t] + shq[3][t]);
    }
}

// ----------------- BN finalize + fold into next W (emits transposed bf16 W'ocm + bias) -----------------
__global__ __launch_bounds__(128) void k_finalize(const float* __restrict__ sum, const float* __restrict__ sumsq,
                                                  const float* __restrict__ gamma, const float* __restrict__ beta,
                                                  const float* __restrict__ Wnext, float* __restrict__ A,
                                                  float* __restrict__ B, unsigned short* __restrict__ WpT,
                                                  float* __restrict__ biasv, int hasNext){
    __shared__ float Ash[128], Bsh[128];
    int c = threadIdx.x;
    const float invN = 1.0f / (float)N_NODESC;
    float mu  = sum[c] * invN;
    float var = sumsq[c] * invN - mu*mu;
    float is  = rsqrtf(var + BN_EPS);
    float a = is * gamma[c];
    float b = beta[c] - mu * a;
    A[c] = a; B[c] = b; Ash[c] = a; Bsh[c] = b;
    __syncthreads();
    if (hasNext){
        float bv = 0.f;
        for (int k = 0; k < 128; k++){
            float w = Wnext[k*128 + c];
            WpT[c*128 + k] = f2bf(Ash[k] * w);   // W'^T[n][k] = A[k]*W[k][n]
            bv = fmaf(Bsh[k], w, bv);
        }
        biasv[c] = bv;
    }
}

// ----------------- readout pooling (max, mean, first), bf16 in, BN applied inline -----------------
__global__ __launch_bounds__(1024) void k_pool(const unsigned short* __restrict__ X, const float* __restrict__ A,
                                               const float* __restrict__ B, float* __restrict__ g){
    __shared__ float shm[8][128];
    __shared__ float shs[8][128];
    int t = threadIdx.x;
    int c = t & 127, sl = t >> 7;    // 8 slices x 100 nodes
    int gr = blockIdx.x;
    float a = A[c], b = B[c];
    const unsigned short* base = X + ((size_t)gr*NPG + sl*100)*HID;
    float mx = -1e30f, sm = 0.f;
    for (int i = 0; i < 100; i++){
        float v = fmaf(bfu(base[(size_t)i*HID + c]), a, b);
        mx = fmaxf(mx, v); sm += v;
    }
    shm[sl][c] = mx; shs[sl][c] = sm;
    if (sl == 0) g[gr*384 + 256 + c] = fmaf(bfu(base[c]), a, b);   // first node
    __syncthreads();
    if (t < 128){
        float m = shm[0][t], s = shs[0][t];
        #pragma unroll
        for (int q = 1; q < 8; q++){ m = fmaxf(m, shm[q][t]); s += shs[q][t]; }
        g[gr*384 + t]       = m;
        g[gr*384 + 128 + t] = s * (1.0f/(float)NPG);
    }
}

// ----------------- MLP + log_softmax -----------------
__global__ __launch_bounds__(512) void k_mlp(const float* __restrict__ g, const float* __restrict__ W1,
                                             const float* __restrict__ b1, const float* __restrict__ W2,
                                             const float* __restrict__ b2, float* __restrict__ out){
    __shared__ float row[384];
    __shared__ float t1[384];
    __shared__ float r0[512], r1[512];
    int t = threadIdx.x, gr = blockIdx.x;
    if (t < 384) row[t] = g[gr*384 + t];
    __syncthreads();
    if (t < 384){
        float acc = b1[t];
        for (int k = 0; k < 384; k++) acc = fmaf(row[k], W1[(size_t)k*384 + t], acc);
        t1[t] = acc;
    }
    __syncthreads();
    float p0 = 0.f, p1 = 0.f;
    if (t < 384){ float v = t1[t]; p0 = v*W2[t*2]; p1 = v*W2[t*2+1]; }
    r0[t] = p0; r1[t] = p1; __syncthreads();
    for (int off = 256; off > 0; off >>= 1){
        if (t < off){ r0[t] += r0[t+off]; r1[t] += r1[t+off]; }
        __syncthreads();
    }
    if (t == 0){
        float o0 = r0[0] + b2[0], o1 = r1[0] + b2[1];
        float m = fmaxf(o0, o1);
        float lse = m + logf(expf(o0 - m) + expf(o1 - m));
        out[gr*2 + 0] = o0 - lse;
        out[gr*2 + 1] = o1 - lse;
    }
}

extern "C" void kernel_launch(void* const* d_in, const int* in_sizes, int n_in,
                              void* d_out, int out_size, void* d_ws, size_t ws_size,
                              hipStream_t stream){
    const float* x     = (const float*)d_in[0];
    const int*   ei    = (const int*)d_in[1];
    const float* Wconv = (const float*)d_in[3];
    const float* bconv = (const float*)d_in[4];
    const float* gamma = (const float*)d_in[5];
    const float* beta  = (const float*)d_in[6];
    const float* W1    = (const float*)d_in[7];
    const float* b1    = (const float*)d_in[8];
    const float* W2    = (const float*)d_in[9];
    const float* b2    = (const float*)d_in[10];
    float* out = (float*)d_out;

    char* p = (char*)d_ws;
    size_t off = 0;
    auto alloc = [&](size_t bytes)->char* {
        char* r = p + off; off += (bytes + 255) & ~(size_t)255; return r;
    };
    unsigned short* buf1 = (unsigned short*)alloc((size_t)N_NODESC*HID*2);  // h = bf16(x@W)
    unsigned short* buf2 = (unsigned short*)alloc((size_t)N_NODESC*HID*2);  // post-agg relu'd bf16
    int*   srcS    = (int*)  alloc((size_t)N_EDGESC*4);
    float* normS   = (float*)alloc((size_t)N_EDGESC*4);
    int*   row_ptr = (int*)  alloc((size_t)(N_NODESC+1)*4);
    int*   deg     = (int*)  alloc((size_t)N_NODESC*4);      // reused as scatter cursor
    float* dinv    = (float*)alloc((size_t)N_NODESC*4);
    int*   chunkTot= (int*)  alloc(512);
    int*   chunkOff= (int*)  alloc(512);
    float* stats   = (float*)alloc(3*2*128*4);               // [l][sum|sumsq][128]
    float* AB      = (float*)alloc(3*2*128*4);               // [l][A|B][128]
    unsigned short* Wt0 = (unsigned short*)alloc(128*128*2); // bf16 W0^T
    unsigned short* WpT = (unsigned short*)alloc(128*128*2); // bf16 BN-folded next-layer W^T
    float* biasv   = (float*)alloc(512);
    float* g       = (float*)alloc((size_t)NUM_GRAPHS*384*4);
    (void)ws_size; (void)in_sizes; (void)n_in; (void)out_size;

    hipMemsetAsync(deg,   0, (size_t)N_NODESC*4, stream);
    hipMemsetAsync(stats, 0, 3*2*128*4, stream);
    hipMemsetAsync(biasv, 0, 512, stream);

    k_count  <<<(N_EDGESC+255)/256, 256, 0, stream>>>(ei, deg);
    k_scan_a <<<N_NODESC/1024, 1024, 0, stream>>>(deg, row_ptr, dinv, chunkTot);
    k_scan_b <<<1, 128, 0, stream>>>(chunkTot, chunkOff, row_ptr);
    k_scan_c <<<N_NODESC/1024, 1024, 0, stream>>>(row_ptr, chunkOff);
    hipMemsetAsync(deg, 0, (size_t)N_NODESC*4, stream);      // cursor for scatter
    k_scatter<<<(N_EDGESC+255)/256, 256, 0, stream>>>(ei, row_ptr, deg, dinv, srcS, normS);
    k_prepw0 <<<64, 256, 0, stream>>>(Wconv, Wt0);

    for (int l = 0; l < 3; l++){
        if (l == 0)
            k_gemm_mfma<1><<<N_NODESC/64, 256, 0, stream>>>((const void*)x, Wt0, biasv, buf1);
        else
            k_gemm_mfma<0><<<N_NODESC/64, 256, 0, stream>>>((const void*)buf2, WpT, biasv, buf1);
        k_agg<<<2048, 256, 0, stream>>>((const unsigned int*)buf1, row_ptr, srcS, normS, dinv,
                                        bconv + l*HID, (unsigned int*)buf2,
                                        stats + l*256, stats + l*256 + 128);
        k_finalize<<<1, 128, 0, stream>>>(stats + l*256, stats + l*256 + 128,
                                          gamma + l*HID, beta + l*HID,
                                          Wconv + (size_t)(l+1 < 3 ? l+1 : 0)*HID*HID,
                                          AB + l*256, AB + l*256 + 128,
                                          WpT, biasv, (l < 2) ? 1 : 0);
    }
    k_pool<<<NUM_GRAPHS, 1024, 0, stream>>>(buf2, AB + 2*256, AB + 2*256 + 128, g);
    k_mlp <<<NUM_GRAPHS, 512, 0, stream>>>(g, W1, b1, W2, b2, out);
}